// Round 10
// baseline (236.718 us; speedup 1.0000x reference)
//
#include <hip/hip_runtime.h>
#include <math.h>

#define NN 50000
#define NE 800000
#define DD 128
#define DOUT 40
#define BN_EPS_F 1e-5f
#define BSTRIDE 128          // bucket slots per node (max deg ~45 for this graph)
#define NPX (NN / 8)         // 6250 nodes per XCD partition
#define EPB 2048             // edges per chunk in bucket build
#define BUCKET_BLOCKS (((NE + EPB - 1) / EPB) * 8)   // 3128
#define X2BF_BLOCKS 6250
#define WPREP_BLOCKS ((5 * 16384 + 255) / 256)       // 320
#define BROWS 96             // rows per mgemm block: grid 521 >= 2x256 CUs (r9 lesson)
#define WROWS 12             // rows per wave (frag rows 12-15 masked)

typedef __attribute__((ext_vector_type(8))) short bf16x8;
typedef __attribute__((ext_vector_type(4))) float f32x4;

static __device__ __forceinline__ unsigned short f2bf(float f) {
  unsigned u = __float_as_uint(f);
  unsigned r = (u + 0x7FFFu + ((u >> 16) & 1u)) >> 16;
  return (unsigned short)r;
}
static __device__ __forceinline__ float bf2f(unsigned short u) {
  return __uint_as_float((unsigned)u << 16);
}

// ---------------- zero cnt + stats ----------------
__global__ void k_zero(int* __restrict__ cnt, float* __restrict__ stats) {
  int i = blockIdx.x * 256 + threadIdx.x;
  if (i < NN) cnt[i] = 0;
  if (i < 4 * DD) stats[i] = 0.f;
}

// ---- fused: XCD-partitioned bucket build | x->bf16 | weight frag shuffle ----
__global__ void k_bucketprep(const int* __restrict__ srcI, const int* __restrict__ dstI,
                             int* __restrict__ cnt, unsigned short* __restrict__ bkt,
                             const float4* __restrict__ x, ushort4* __restrict__ xb,
                             const float* __restrict__ W0, const float* __restrict__ W1,
                             const float* __restrict__ W2, const float* __restrict__ W3,
                             const float* __restrict__ W4, unsigned short* __restrict__ wf) {
  int b = blockIdx.x;
  if (b < BUCKET_BLOCKS) {
    int xcd = b & 7;
    int chunk = b >> 3;
    int lo = xcd * NPX, hi = lo + NPX;
    int base = chunk * EPB + threadIdx.x;
#pragma unroll
    for (int i = 0; i < EPB / 256; i++) {
      int e = base + i * 256;
      if (e < NE) {
        int d = dstI[e];
        if (d >= lo && d < hi) {
          int r = atomicAdd(&cnt[d], 1);
          if (r < BSTRIDE) bkt[(size_t)d * BSTRIDE + r] = (unsigned short)srcI[e];
        }
      }
    }
  } else if (b < BUCKET_BLOCKS + X2BF_BLOCKS) {
    int i = (b - BUCKET_BLOCKS) * 256 + threadIdx.x;
    if (i < NN * 32) {
      float4 v = x[i];
      ushort4 r;
      r.x = f2bf(v.x); r.y = f2bf(v.y); r.z = f2bf(v.z); r.w = f2bf(v.w);
      xb[i] = r;
    }
  } else {
    int fid = (b - BUCKET_BLOCKS - X2BF_BLOCKS) * 256 + threadIdx.x;
    if (fid >= 5 * 16384) return;
    int g = fid >> 14;
    int r = fid & 16383;
    int i = r & 7;
    int lane = (r >> 3) & 63;
    int ks = (r >> 9) & 3;
    int ct = r >> 11;
    int k = ks * 32 + (lane >> 4) * 8 + i;
    int col = ct * 16 + (lane & 15);
    const float* Wp = (g == 0) ? W0 : (g == 1) ? W1 : (g == 2) ? W2 : (g == 3) ? W3 : W4;
    float w = Wp[k * DD + col];
    unsigned short hi = f2bf(w);
    unsigned short lo = f2bf(w - bf2f(hi));
    wf[g * 32768 + r] = hi;
    wf[g * 32768 + 16384 + r] = lo;
  }
}

// ---------------- bf16 gather aggregation over buckets (32 lanes/row) ----------------
// reverted from fused-AGGR (r9): per-wave 2-node pattern gathers full 256B rows
__global__ void k_aggr_bf(const ushort4* __restrict__ x, const int* __restrict__ cnt,
                          const unsigned short* __restrict__ bkt,
                          ushort4* __restrict__ out) {
  int tid = blockIdx.x * 256 + threadIdx.x;
  int node = tid >> 5;
  if (node >= NN) return;
  int c = tid & 31;
  int cn = cnt[node];
  cn = (cn < BSTRIDE) ? cn : BSTRIDE;
  const unsigned short* bp = bkt + (size_t)node * BSTRIDE;
  ushort4 sv = x[node * 32 + c];
  float ax = bf2f(sv.x), ay = bf2f(sv.y), az = bf2f(sv.z), aw = bf2f(sv.w);
  int j = 0;
  for (; j + 3 < cn; j += 4) {
    int s0 = bp[j], s1 = bp[j + 1], s2 = bp[j + 2], s3 = bp[j + 3];
    ushort4 v0 = x[s0 * 32 + c];
    ushort4 v1 = x[s1 * 32 + c];
    ushort4 v2 = x[s2 * 32 + c];
    ushort4 v3 = x[s3 * 32 + c];
    ax += bf2f(v0.x) + bf2f(v1.x) + bf2f(v2.x) + bf2f(v3.x);
    ay += bf2f(v0.y) + bf2f(v1.y) + bf2f(v2.y) + bf2f(v3.y);
    az += bf2f(v0.z) + bf2f(v1.z) + bf2f(v2.z) + bf2f(v3.z);
    aw += bf2f(v0.w) + bf2f(v1.w) + bf2f(v2.w) + bf2f(v3.w);
  }
  for (; j < cn; j++) {
    int s0 = bp[j];
    ushort4 v0 = x[s0 * 32 + c];
    ax += bf2f(v0.x); ay += bf2f(v0.y); az += bf2f(v0.z); aw += bf2f(v0.w);
  }
  ushort4 r;
  r.x = f2bf(ax); r.y = f2bf(ay); r.z = f2bf(az); r.w = f2bf(aw);
  out[node * 32 + c] = r;
}

// ------- MFMA GEMM, bf16 activations; W = hi+lo split (A*Whi + A*Wlo = A*W exact) ----
// 512 threads = 8 waves x 12 rows (96 rows/block, grid 521 for 2-block/CU fill).
// Frag rows 12-15 overlap the next wave's rows: computed but masked at store/stats.
template<bool BN_IN, bool RELU_OUT, bool STATS_OUT, bool HEAD>
__global__ __launch_bounds__(512) void k_mgemm(
    const unsigned short* __restrict__ in, const unsigned short* __restrict__ wf,
    const float* __restrict__ bias, float* __restrict__ outF,
    unsigned short* __restrict__ outB,
    const float* __restrict__ statsIn, float* __restrict__ statsOut,
    const float* __restrict__ gamma, const float* __restrict__ beta,
    const float* __restrict__ W2h, const float* __restrict__ b2h) {
  __shared__ __align__(16) char smem[65536];   // W frags; HEAD reuses as h-tile + W2
  __shared__ float scs[DD], shs[DD], lbias[DD], ls[DD], lq[DD];
  short* lw = (short*)smem;
  int tid = threadIdx.x;
  int lane = tid & 63, wv = tid >> 6;
  int rbase = blockIdx.x * BROWS + wv * WROWS;
  int kq = (lane >> 4) * 8;

  // ---- A prefetch (before W staging to overlap round trips) ----
  bf16x8 araw[4];
  {
    int row = rbase + (lane & 15);
    bool v = row < NN;
    const unsigned short* ap = in + (size_t)row * DD + kq;
    bf16x8 zz = {0, 0, 0, 0, 0, 0, 0, 0};
#pragma unroll
    for (int ks = 0; ks < 4; ks++)
      araw[ks] = v ? *(const bf16x8*)(ap + ks * 32) : zz;
  }

  // ---- W staging: 64 KB, 8 float4 per thread ----
  {
    const float4* src = (const float4*)wf;
    float4* dst = (float4*)lw;
#pragma unroll
    for (int it = 0; it < 8; it++) dst[it * 512 + tid] = src[it * 512 + tid];
  }
  if (tid < DD) {
    lbias[tid] = bias[tid];
    if (STATS_OUT) { ls[tid] = 0.f; lq[tid] = 0.f; }
    if (BN_IN) {
      float mu  = statsIn[tid] * (1.0f / NN);
      float var = statsIn[DD + tid] * (1.0f / NN) - mu * mu;
      float sc  = gamma[tid] * rsqrtf(var + BN_EPS_F);
      scs[tid] = sc;
      shs[tid] = beta[tid] - mu * sc;
    }
  }
  __syncthreads();

  bf16x8 ahi[4];
  if constexpr (BN_IN) {
#pragma unroll
    for (int ks = 0; ks < 4; ks++) {
      const float4* s4 = (const float4*)&scs[ks * 32 + kq];
      const float4* h4 = (const float4*)&shs[ks * 32 + kq];
      float4 sa = s4[0], sb = s4[1], ha = h4[0], hb = h4[1];
      float ss[8] = {sa.x, sa.y, sa.z, sa.w, sb.x, sb.y, sb.z, sb.w};
      float hh[8] = {ha.x, ha.y, ha.z, ha.w, hb.x, hb.y, hb.z, hb.w};
      bf16x8 h;
#pragma unroll
      for (int i = 0; i < 8; i++) {
        float xv = fmaxf(bf2f((unsigned short)araw[ks][i]) * ss[i] + hh[i], 0.f);
        h[i] = (short)f2bf(xv);
      }
      ahi[ks] = h;
    }
  } else {
#pragma unroll
    for (int ks = 0; ks < 4; ks++) ahi[ks] = araw[ks];
  }

  // ---- MFMA main loop: 64 MFMAs/wave ----
  f32x4 acc[8];
#pragma unroll
  for (int ct = 0; ct < 8; ct++) acc[ct] = (f32x4){0.f, 0.f, 0.f, 0.f};
  const bf16x8* lwv = (const bf16x8*)lw;
#pragma unroll
  for (int ks = 0; ks < 4; ks++) {
#pragma unroll
    for (int ct = 0; ct < 8; ct++) {
      bf16x8 bh = lwv[(ct * 4 + ks) * 64 + lane];
      bf16x8 bl = lwv[2048 + (ct * 4 + ks) * 64 + lane];
      acc[ct] = __builtin_amdgcn_mfma_f32_16x16x32_bf16(ahi[ks], bh, acc[ct], 0, 0, 0);
      acc[ct] = __builtin_amdgcn_mfma_f32_16x16x32_bf16(ahi[ks], bl, acc[ct], 0, 0, 0);
    }
  }

  // ---- epilogue ----  C/D layout: col = lane&15, row = (lane>>4)*4 + reg
  if constexpr (!HEAD) {
    int fr0 = (lane >> 4) * 4;
    int r0 = rbase + fr0;
#pragma unroll
    for (int ct = 0; ct < 8; ct++) {
      int col = ct * 16 + (lane & 15);
      float bb = lbias[col];
      float s = 0.f, q = 0.f;
#pragma unroll
      for (int j = 0; j < 4; j++) {
        int fr = fr0 + j;
        int row = r0 + j;
        if (fr < WROWS && row < NN) {     // mask duplicate frag rows 12-15
          float v = acc[ct][j] + bb;
          if (RELU_OUT) v = fmaxf(v, 0.f);
          outB[(size_t)row * DD + col] = f2bf(v);
          if (STATS_OUT) { s += v; q += v * v; }
        }
      }
      if (STATS_OUT) {
        s += __shfl_xor(s, 16); s += __shfl_xor(s, 32);
        q += __shfl_xor(q, 16); q += __shfl_xor(q, 32);
        if ((lane >> 4) == 0) {
          atomicAdd(&ls[col], s);
          atomicAdd(&lq[col], q);
        }
      }
    }
    if (STATS_OUT) {
      __syncthreads();
      if (tid < DD) {
        atomicAdd(&statsOut[tid], ls[tid]);
        atomicAdd(&statsOut[DD + tid], lq[tid]);
      }
    }
  } else {
    // ---- fused head ----
    unsigned short* hs = (unsigned short*)smem;        // [96][132] bf16
    float* W2s = (float*)(smem + 33792);               // [128][40] f32
    __syncthreads();                                   // all waves done reading lw
    {
      int fr0 = (lane >> 4) * 4;
      int lr0 = wv * WROWS + fr0;
#pragma unroll
      for (int ct = 0; ct < 8; ct++) {
        int col = ct * 16 + (lane & 15);
        float bb = lbias[col];
#pragma unroll
        for (int j = 0; j < 4; j++) {
          if (fr0 + j < WROWS) {
            float v = fmaxf(acc[ct][j] + bb, 0.f);
            hs[(lr0 + j) * 132 + col] = f2bf(v);
          }
        }
      }
      const float4* W2g = (const float4*)W2h;
      float4* W2s4 = (float4*)W2s;
#pragma unroll
      for (int it = 0; it < 3; it++) {
        int idx = it * 512 + tid;
        if (idx < 1280) W2s4[idx] = W2g[idx];
      }
    }
    __syncthreads();
    int lrow = tid >> 2, q = tid & 3;
    int grow = blockIdx.x * BROWS + lrow;
    bool act = (lrow < BROWS) && (grow < NN);
    float a2[40];
#pragma unroll
    for (int j = 0; j < 40; j++) a2[j] = 0.f;
    if (act) {
      for (int kk = 0; kk < 32; kk++) {
        int k = kk * 4 + q;
        float hv = bf2f(hs[lrow * 132 + k]);
        const float4* wrow = (const float4*)(W2s + k * DOUT);
#pragma unroll
        for (int j4 = 0; j4 < 10; j4++) {
          float4 w = wrow[j4];
          a2[j4 * 4 + 0] += hv * w.x;
          a2[j4 * 4 + 1] += hv * w.y;
          a2[j4 * 4 + 2] += hv * w.z;
          a2[j4 * 4 + 3] += hv * w.w;
        }
      }
    }
#pragma unroll
    for (int j = 0; j < 40; j++) {
      a2[j] += __shfl_xor(a2[j], 1);
      a2[j] += __shfl_xor(a2[j], 2);
    }
    if (q == 0 && act) {
      const float4* b24 = (const float4*)b2h;
      float m = -INFINITY;
#pragma unroll
      for (int j4 = 0; j4 < 10; j4++) {
        float4 bb = b24[j4];
        a2[j4 * 4 + 0] += bb.x; a2[j4 * 4 + 1] += bb.y;
        a2[j4 * 4 + 2] += bb.z; a2[j4 * 4 + 3] += bb.w;
      }
#pragma unroll
      for (int j = 0; j < 40; j++) m = fmaxf(m, a2[j]);
      float s = 0.f;
#pragma unroll
      for (int j = 0; j < 40; j++) s += expf(a2[j] - m);
      float d = m + logf(s);
      float4* out4 = (float4*)(outF + (size_t)grow * DOUT);
#pragma unroll
      for (int j4 = 0; j4 < 10; j4++) {
        float4 v = make_float4(a2[j4 * 4 + 0] - d, a2[j4 * 4 + 1] - d,
                               a2[j4 * 4 + 2] - d, a2[j4 * 4 + 3] - d);
        out4[j4] = v;
      }
    }
  }
}

extern "C" void kernel_launch(void* const* d_in, const int* in_sizes, int n_in,
                              void* d_out, int out_size, void* d_ws, size_t ws_size,
                              hipStream_t stream) {
  const float* x   = (const float*)d_in[0];
  const int*   ei  = (const int*)d_in[1];
  const float* W1a = (const float*)d_in[2];
  const float* b1a = (const float*)d_in[3];
  const float* g1  = (const float*)d_in[4];
  const float* be1 = (const float*)d_in[5];
  const float* W2a = (const float*)d_in[6];
  const float* b2a = (const float*)d_in[7];
  const float* W1b = (const float*)d_in[8];
  const float* b1b = (const float*)d_in[9];
  const float* g2  = (const float*)d_in[10];
  const float* be2 = (const float*)d_in[11];
  const float* W2b = (const float*)d_in[12];
  const float* b2b = (const float*)d_in[13];
  const float* Wl1 = (const float*)d_in[14];
  const float* bl1 = (const float*)d_in[15];
  const float* Wl2 = (const float*)d_in[16];
  const float* bl2 = (const float*)d_in[17];
  float* out = (float*)d_out;

  unsigned short* bufX = (unsigned short*)d_ws;           // N x 128 bf16
  unsigned short* bufA = bufX + (size_t)NN * DD;          // N x 128 bf16
  unsigned short* bufB = bufA + (size_t)NN * DD;          // N x 128 bf16
  float* stats1 = (float*)(bufB + (size_t)NN * DD);       // 256
  float* stats2 = stats1 + 2 * DD;                        // 256
  int*   cnt    = (int*)(stats2 + 2 * DD);                // N
  unsigned short* bkt = (unsigned short*)(cnt + NN);      // N x BSTRIDE
  size_t wfOff = (((size_t)(bkt + (size_t)NN * BSTRIDE) - (size_t)d_ws) + 15) & ~(size_t)15;
  unsigned short* wfrag = (unsigned short*)((char*)d_ws + wfOff);

  const int* srcI = ei;
  const int* dstI = ei + NE;

  dim3 blk(256);
  int aggrGrid = (NN * 32 + 255) / 256;                  // 6250
  int gemmGrid = (NN + BROWS - 1) / BROWS;               // 521
  int bpGrid   = BUCKET_BLOCKS + X2BF_BLOCKS + WPREP_BLOCKS;
  int zeroGrid = (NN + 255) / 256;

  // ---- setup ----
  k_zero<<<zeroGrid, blk, 0, stream>>>(cnt, stats1);
  k_bucketprep<<<bpGrid, blk, 0, stream>>>(srcI, dstI, cnt, bkt, (const float4*)x,
                                           (ushort4*)bufX, W1a, W2a, W1b, W2b, Wl1, wfrag);

  // ---- conv1 ----
  k_aggr_bf<<<aggrGrid, blk, 0, stream>>>((const ushort4*)bufX, cnt, bkt, (ushort4*)bufA);
  k_mgemm<false, false, true, false><<<gemmGrid, 512, 0, stream>>>(
      bufA, wfrag + 0 * 32768, b1a, nullptr, bufB,
      nullptr, stats1, nullptr, nullptr, nullptr, nullptr);
  k_mgemm<true, true, false, false><<<gemmGrid, 512, 0, stream>>>(
      bufB, wfrag + 1 * 32768, b2a, nullptr, bufA,
      stats1, nullptr, g1, be1, nullptr, nullptr);
  // ---- conv2 ----
  k_aggr_bf<<<aggrGrid, blk, 0, stream>>>((const ushort4*)bufA, cnt, bkt, (ushort4*)bufB);
  k_mgemm<false, false, true, false><<<gemmGrid, 512, 0, stream>>>(
      bufB, wfrag + 2 * 32768, b1b, nullptr, bufA,
      nullptr, stats2, nullptr, nullptr, nullptr, nullptr);
  k_mgemm<true, true, false, false><<<gemmGrid, 512, 0, stream>>>(
      bufA, wfrag + 3 * 32768, b2b, nullptr, bufB,
      stats2, nullptr, g2, be2, nullptr, nullptr);
  // ---- fused head ----
  k_mgemm<false, false, true, true><<<gemmGrid, 512, 0, stream>>>(
      bufB, wfrag + 4 * 32768, bl1, out, nullptr,
      nullptr, nullptr, nullptr, nullptr, Wl2, bl2);
}

// Round 11
// 203.885 us; speedup vs baseline: 1.1610x; 1.1610x over previous
//
#include <hip/hip_runtime.h>
#include <math.h>

#define NN 50000
#define NE 800000
#define DD 128
#define DOUT 40
#define BN_EPS_F 1e-5f
#define BSTRIDE 64           // bucket slots per node (max deg ~45; P(>64) ~ 1e-14)
#define NPX (NN / 8)         // 6250 nodes per XCD partition
#define EPB 1024             // edges per chunk: 4 edges/thread via int4, 1 iter
#define BUCKET_BLOCKS (((NE + EPB - 1) / EPB) * 8)   // 782 * 8 = 6256
#define X2BF_BLOCKS 6250
#define WPREP_BLOCKS ((5 * 16384 + 255) / 256)       // 320

typedef __attribute__((ext_vector_type(8))) short bf16x8;
typedef __attribute__((ext_vector_type(4))) float f32x4;

static __device__ __forceinline__ unsigned short f2bf(float f) {
  unsigned u = __float_as_uint(f);
  unsigned r = (u + 0x7FFFu + ((u >> 16) & 1u)) >> 16;
  return (unsigned short)r;
}
static __device__ __forceinline__ float bf2f(unsigned short u) {
  return __uint_as_float((unsigned)u << 16);
}

// ---------------- zero cnt + stats ----------------
__global__ void k_zero(int* __restrict__ cnt, float* __restrict__ stats) {
  int i = blockIdx.x * 256 + threadIdx.x;
  if (i < NN) cnt[i] = 0;
  if (i < 4 * DD) stats[i] = 0.f;
}

// ---- fused: XCD-partitioned bucket build | x->bf16 | weight frag shuffle ----
// bucket: blockIdx&7 = XCD-owned dst range; int4 edge loads -> 4 independent
// atomic chains per thread, 1 iteration (r10 lesson: latency-bound, widen ILP).
__global__ void k_bucketprep(const int* __restrict__ srcI, const int* __restrict__ dstI,
                             int* __restrict__ cnt, unsigned short* __restrict__ bkt,
                             const float4* __restrict__ x, ushort4* __restrict__ xb,
                             const float* __restrict__ W0, const float* __restrict__ W1,
                             const float* __restrict__ W2, const float* __restrict__ W3,
                             const float* __restrict__ W4, unsigned short* __restrict__ wf) {
  int b = blockIdx.x;
  if (b < BUCKET_BLOCKS) {
    int xcd = b & 7;
    int chunk = b >> 3;
    int lo = xcd * NPX, hi = lo + NPX;
    int e0 = chunk * EPB + threadIdx.x * 4;
    if (e0 < NE) {                       // NE%4==0: int4 never straddles the end
      int4 d4 = *(const int4*)(dstI + e0);
      int4 s4 = *(const int4*)(srcI + e0);
      int dd[4] = {d4.x, d4.y, d4.z, d4.w};
      int ss[4] = {s4.x, s4.y, s4.z, s4.w};
#pragma unroll
      for (int i = 0; i < 4; i++) {
        int d = dd[i];
        if (d >= lo && d < hi) {
          int r = atomicAdd(&cnt[d], 1);
          if (r < BSTRIDE) bkt[(size_t)d * BSTRIDE + r] = (unsigned short)ss[i];
        }
      }
    }
  } else if (b < BUCKET_BLOCKS + X2BF_BLOCKS) {
    int i = (b - BUCKET_BLOCKS) * 256 + threadIdx.x;
    if (i < NN * 32) {
      float4 v = x[i];
      ushort4 r;
      r.x = f2bf(v.x); r.y = f2bf(v.y); r.z = f2bf(v.z); r.w = f2bf(v.w);
      xb[i] = r;
    }
  } else {
    int fid = (b - BUCKET_BLOCKS - X2BF_BLOCKS) * 256 + threadIdx.x;
    if (fid >= 5 * 16384) return;
    int g = fid >> 14;
    int r = fid & 16383;
    int i = r & 7;
    int lane = (r >> 3) & 63;
    int ks = (r >> 9) & 3;
    int ct = r >> 11;
    int k = ks * 32 + (lane >> 4) * 8 + i;
    int col = ct * 16 + (lane & 15);
    const float* Wp = (g == 0) ? W0 : (g == 1) ? W1 : (g == 2) ? W2 : (g == 3) ? W3 : W4;
    float w = Wp[k * DD + col];
    unsigned short hi = f2bf(w);
    unsigned short lo = f2bf(w - bf2f(hi));
    wf[g * 32768 + r] = hi;
    wf[g * 32768 + 16384 + r] = lo;
  }
}

// ---------------- bf16 gather aggregation over buckets (32 lanes/row) ----------------
__global__ void k_aggr_bf(const ushort4* __restrict__ x, const int* __restrict__ cnt,
                          const unsigned short* __restrict__ bkt,
                          ushort4* __restrict__ out) {
  int tid = blockIdx.x * 256 + threadIdx.x;
  int node = tid >> 5;
  if (node >= NN) return;
  int c = tid & 31;
  int cn = cnt[node];
  cn = (cn < BSTRIDE) ? cn : BSTRIDE;
  const unsigned short* bp = bkt + (size_t)node * BSTRIDE;
  ushort4 sv = x[node * 32 + c];
  float ax = bf2f(sv.x), ay = bf2f(sv.y), az = bf2f(sv.z), aw = bf2f(sv.w);
  int j = 0;
  for (; j + 3 < cn; j += 4) {
    int s0 = bp[j], s1 = bp[j + 1], s2 = bp[j + 2], s3 = bp[j + 3];
    ushort4 v0 = x[s0 * 32 + c];
    ushort4 v1 = x[s1 * 32 + c];
    ushort4 v2 = x[s2 * 32 + c];
    ushort4 v3 = x[s3 * 32 + c];
    ax += bf2f(v0.x) + bf2f(v1.x) + bf2f(v2.x) + bf2f(v3.x);
    ay += bf2f(v0.y) + bf2f(v1.y) + bf2f(v2.y) + bf2f(v3.y);
    az += bf2f(v0.z) + bf2f(v1.z) + bf2f(v2.z) + bf2f(v3.z);
    aw += bf2f(v0.w) + bf2f(v1.w) + bf2f(v2.w) + bf2f(v3.w);
  }
  for (; j < cn; j++) {
    int s0 = bp[j];
    ushort4 v0 = x[s0 * 32 + c];
    ax += bf2f(v0.x); ay += bf2f(v0.y); az += bf2f(v0.z); aw += bf2f(v0.w);
  }
  ushort4 r;
  r.x = f2bf(ax); r.y = f2bf(ay); r.z = f2bf(az); r.w = f2bf(aw);
  out[node * 32 + c] = r;
}

// ------- MFMA GEMM, bf16 activations; W = hi+lo split (A*Whi + A*Wlo = A*W exact) ----
// 512 threads = 8 waves x 16 rows, 128 rows/block, grid 391.
// (r10 lesson: W-staging traffic scales with grid — keep 391, not 521.)
template<bool BN_IN, bool RELU_OUT, bool STATS_OUT, bool HEAD>
__global__ __launch_bounds__(512) void k_mgemm(
    const unsigned short* __restrict__ in, const unsigned short* __restrict__ wf,
    const float* __restrict__ bias, float* __restrict__ outF,
    unsigned short* __restrict__ outB,
    const float* __restrict__ statsIn, float* __restrict__ statsOut,
    const float* __restrict__ gamma, const float* __restrict__ beta,
    const float* __restrict__ W2h, const float* __restrict__ b2h) {
  __shared__ __align__(16) char smem[65536];   // W frags; HEAD reuses as h-tile + W2
  __shared__ float scs[DD], shs[DD], lbias[DD], ls[DD], lq[DD];
  short* lw = (short*)smem;
  int tid = threadIdx.x;
  int lane = tid & 63, wv = tid >> 6;
  int rbase = blockIdx.x * 128 + wv * 16;
  int kq = (lane >> 4) * 8;

  // ---- A prefetch (before W staging to overlap round trips) ----
  bf16x8 araw[4];
  {
    int row = rbase + (lane & 15);
    bool v = row < NN;
    const unsigned short* ap = in + (size_t)row * DD + kq;
    bf16x8 zz = {0, 0, 0, 0, 0, 0, 0, 0};
#pragma unroll
    for (int ks = 0; ks < 4; ks++)
      araw[ks] = v ? *(const bf16x8*)(ap + ks * 32) : zz;
  }

  // ---- W staging: 64 KB, 8 float4 per thread ----
  {
    const float4* src = (const float4*)wf;
    float4* dst = (float4*)lw;
#pragma unroll
    for (int it = 0; it < 8; it++) dst[it * 512 + tid] = src[it * 512 + tid];
  }
  if (tid < DD) {
    lbias[tid] = bias[tid];
    if (STATS_OUT) { ls[tid] = 0.f; lq[tid] = 0.f; }
    if (BN_IN) {
      float mu  = statsIn[tid] * (1.0f / NN);
      float var = statsIn[DD + tid] * (1.0f / NN) - mu * mu;
      float sc  = gamma[tid] * rsqrtf(var + BN_EPS_F);
      scs[tid] = sc;
      shs[tid] = beta[tid] - mu * sc;
    }
  }
  __syncthreads();

  bf16x8 ahi[4];
  if constexpr (BN_IN) {
#pragma unroll
    for (int ks = 0; ks < 4; ks++) {
      const float4* s4 = (const float4*)&scs[ks * 32 + kq];
      const float4* h4 = (const float4*)&shs[ks * 32 + kq];
      float4 sa = s4[0], sb = s4[1], ha = h4[0], hb = h4[1];
      float ss[8] = {sa.x, sa.y, sa.z, sa.w, sb.x, sb.y, sb.z, sb.w};
      float hh[8] = {ha.x, ha.y, ha.z, ha.w, hb.x, hb.y, hb.z, hb.w};
      bf16x8 h;
#pragma unroll
      for (int i = 0; i < 8; i++) {
        float xv = fmaxf(bf2f((unsigned short)araw[ks][i]) * ss[i] + hh[i], 0.f);
        h[i] = (short)f2bf(xv);
      }
      ahi[ks] = h;
    }
  } else {
#pragma unroll
    for (int ks = 0; ks < 4; ks++) ahi[ks] = araw[ks];
  }

  // ---- MFMA main loop: 64 MFMAs/wave ----
  f32x4 acc[8];
#pragma unroll
  for (int ct = 0; ct < 8; ct++) acc[ct] = (f32x4){0.f, 0.f, 0.f, 0.f};
  const bf16x8* lwv = (const bf16x8*)lw;
#pragma unroll
  for (int ks = 0; ks < 4; ks++) {
#pragma unroll
    for (int ct = 0; ct < 8; ct++) {
      bf16x8 bh = lwv[(ct * 4 + ks) * 64 + lane];
      bf16x8 bl = lwv[2048 + (ct * 4 + ks) * 64 + lane];
      acc[ct] = __builtin_amdgcn_mfma_f32_16x16x32_bf16(ahi[ks], bh, acc[ct], 0, 0, 0);
      acc[ct] = __builtin_amdgcn_mfma_f32_16x16x32_bf16(ahi[ks], bl, acc[ct], 0, 0, 0);
    }
  }

  // ---- epilogue ----  C/D layout: col = lane&15, row = (lane>>4)*4 + reg
  if constexpr (!HEAD) {
    int r0 = rbase + (lane >> 4) * 4;
#pragma unroll
    for (int ct = 0; ct < 8; ct++) {
      int col = ct * 16 + (lane & 15);
      float bb = lbias[col];
      float s = 0.f, q = 0.f;
#pragma unroll
      for (int j = 0; j < 4; j++) {
        int row = r0 + j;
        if (row < NN) {
          float v = acc[ct][j] + bb;
          if (RELU_OUT) v = fmaxf(v, 0.f);
          outB[(size_t)row * DD + col] = f2bf(v);
          if (STATS_OUT) { s += v; q += v * v; }
        }
      }
      if (STATS_OUT) {
        s += __shfl_xor(s, 16); s += __shfl_xor(s, 32);
        q += __shfl_xor(q, 16); q += __shfl_xor(q, 32);
        if ((lane >> 4) == 0) {
          atomicAdd(&ls[col], s);
          atomicAdd(&lq[col], q);
        }
      }
    }
    if (STATS_OUT) {
      __syncthreads();
      if (tid < DD) {
        atomicAdd(&statsOut[tid], ls[tid]);
        atomicAdd(&statsOut[DD + tid], lq[tid]);
      }
    }
  } else {
    // ---- fused head ----
    unsigned short* hs = (unsigned short*)smem;        // [128][132] bf16
    float* W2s = (float*)(smem + 33792);               // [128][40] f32
    __syncthreads();                                   // all waves done reading lw
    {
      int lr0 = wv * 16 + (lane >> 4) * 4;
#pragma unroll
      for (int ct = 0; ct < 8; ct++) {
        int col = ct * 16 + (lane & 15);
        float bb = lbias[col];
#pragma unroll
        for (int j = 0; j < 4; j++) {
          float v = fmaxf(acc[ct][j] + bb, 0.f);
          hs[(lr0 + j) * 132 + col] = f2bf(v);
        }
      }
      const float4* W2g = (const float4*)W2h;
      float4* W2s4 = (float4*)W2s;
#pragma unroll
      for (int it = 0; it < 3; it++) {
        int idx = it * 512 + tid;
        if (idx < 1280) W2s4[idx] = W2g[idx];
      }
    }
    __syncthreads();
    int lrow = tid >> 2, q = tid & 3;
    int grow = blockIdx.x * 128 + lrow;
    float a2[40];
#pragma unroll
    for (int j = 0; j < 40; j++) a2[j] = 0.f;
    for (int kk = 0; kk < 32; kk++) {
      int k = kk * 4 + q;
      float hv = bf2f(hs[lrow * 132 + k]);
      const float4* wrow = (const float4*)(W2s + k * DOUT);
#pragma unroll
      for (int j4 = 0; j4 < 10; j4++) {
        float4 w = wrow[j4];
        a2[j4 * 4 + 0] += hv * w.x;
        a2[j4 * 4 + 1] += hv * w.y;
        a2[j4 * 4 + 2] += hv * w.z;
        a2[j4 * 4 + 3] += hv * w.w;
      }
    }
#pragma unroll
    for (int j = 0; j < 40; j++) {
      a2[j] += __shfl_xor(a2[j], 1);
      a2[j] += __shfl_xor(a2[j], 2);
    }
    if (q == 0 && grow < NN) {
      const float4* b24 = (const float4*)b2h;
      float m = -INFINITY;
#pragma unroll
      for (int j4 = 0; j4 < 10; j4++) {
        float4 bb = b24[j4];
        a2[j4 * 4 + 0] += bb.x; a2[j4 * 4 + 1] += bb.y;
        a2[j4 * 4 + 2] += bb.z; a2[j4 * 4 + 3] += bb.w;
      }
#pragma unroll
      for (int j = 0; j < 40; j++) m = fmaxf(m, a2[j]);
      float s = 0.f;
#pragma unroll
      for (int j = 0; j < 40; j++) s += expf(a2[j] - m);
      float d = m + logf(s);
      float4* out4 = (float4*)(outF + (size_t)grow * DOUT);
#pragma unroll
      for (int j4 = 0; j4 < 10; j4++) {
        float4 v = make_float4(a2[j4 * 4 + 0] - d, a2[j4 * 4 + 1] - d,
                               a2[j4 * 4 + 2] - d, a2[j4 * 4 + 3] - d);
        out4[j4] = v;
      }
    }
  }
}

extern "C" void kernel_launch(void* const* d_in, const int* in_sizes, int n_in,
                              void* d_out, int out_size, void* d_ws, size_t ws_size,
                              hipStream_t stream) {
  const float* x   = (const float*)d_in[0];
  const int*   ei  = (const int*)d_in[1];
  const float* W1a = (const float*)d_in[2];
  const float* b1a = (const float*)d_in[3];
  const float* g1  = (const float*)d_in[4];
  const float* be1 = (const float*)d_in[5];
  const float* W2a = (const float*)d_in[6];
  const float* b2a = (const float*)d_in[7];
  const float* W1b = (const float*)d_in[8];
  const float* b1b = (const float*)d_in[9];
  const float* g2  = (const float*)d_in[10];
  const float* be2 = (const float*)d_in[11];
  const float* W2b = (const float*)d_in[12];
  const float* b2b = (const float*)d_in[13];
  const float* Wl1 = (const float*)d_in[14];
  const float* bl1 = (const float*)d_in[15];
  const float* Wl2 = (const float*)d_in[16];
  const float* bl2 = (const float*)d_in[17];
  float* out = (float*)d_out;

  unsigned short* bufX = (unsigned short*)d_ws;           // N x 128 bf16
  unsigned short* bufA = bufX + (size_t)NN * DD;          // N x 128 bf16
  unsigned short* bufB = bufA + (size_t)NN * DD;          // N x 128 bf16
  float* stats1 = (float*)(bufB + (size_t)NN * DD);       // 256
  float* stats2 = stats1 + 2 * DD;                        // 256
  int*   cnt    = (int*)(stats2 + 2 * DD);                // N
  unsigned short* bkt = (unsigned short*)(cnt + NN);      // N x BSTRIDE
  size_t wfOff = (((size_t)(bkt + (size_t)NN * BSTRIDE) - (size_t)d_ws) + 15) & ~(size_t)15;
  unsigned short* wfrag = (unsigned short*)((char*)d_ws + wfOff);

  const int* srcI = ei;
  const int* dstI = ei + NE;

  dim3 blk(256);
  int aggrGrid = (NN * 32 + 255) / 256;                  // 6250
  int gemmGrid = (NN + 127) / 128;                       // 391
  int bpGrid   = BUCKET_BLOCKS + X2BF_BLOCKS + WPREP_BLOCKS;
  int zeroGrid = (NN + 255) / 256;

  // ---- setup ----
  k_zero<<<zeroGrid, blk, 0, stream>>>(cnt, stats1);
  k_bucketprep<<<bpGrid, blk, 0, stream>>>(srcI, dstI, cnt, bkt, (const float4*)x,
                                           (ushort4*)bufX, W1a, W2a, W1b, W2b, Wl1, wfrag);

  // ---- conv1 ----
  k_aggr_bf<<<aggrGrid, blk, 0, stream>>>((const ushort4*)bufX, cnt, bkt, (ushort4*)bufA);
  k_mgemm<false, false, true, false><<<gemmGrid, 512, 0, stream>>>(
      bufA, wfrag + 0 * 32768, b1a, nullptr, bufB,
      nullptr, stats1, nullptr, nullptr, nullptr, nullptr);
  k_mgemm<true, true, false, false><<<gemmGrid, 512, 0, stream>>>(
      bufB, wfrag + 1 * 32768, b2a, nullptr, bufA,
      stats1, nullptr, g1, be1, nullptr, nullptr);
  // ---- conv2 ----
  k_aggr_bf<<<aggrGrid, blk, 0, stream>>>((const ushort4*)bufA, cnt, bkt, (ushort4*)bufB);
  k_mgemm<false, false, true, false><<<gemmGrid, 512, 0, stream>>>(
      bufB, wfrag + 2 * 32768, b1b, nullptr, bufA,
      nullptr, stats2, nullptr, nullptr, nullptr, nullptr);
  k_mgemm<true, true, false, false><<<gemmGrid, 512, 0, stream>>>(
      bufA, wfrag + 3 * 32768, b2b, nullptr, bufB,
      stats2, nullptr, g2, be2, nullptr, nullptr);
  // ---- fused head ----
  k_mgemm<false, false, true, true><<<gemmGrid, 512, 0, stream>>>(
      bufB, wfrag + 4 * 32768, bl1, out, nullptr,
      nullptr, nullptr, nullptr, nullptr, Wl2, bl2);
}